// Round 1
// baseline (6493.600 us; speedup 1.0000x reference)
//
#include <hip/hip_runtime.h>
#include <math.h>

#define B_ROWS 16384
#define F 48
#define T 512
#define LAYERS 16

// workspace layout (float offsets)
#define OFF_PMAX 0
#define OFF_SCALE 256               // [0]=5/max, [1]=max/5
#define OFF_SUMS 512                // LAYERS*T
#define OFF_G    (OFF_SUMS + LAYERS*T)
#define OFF_TAB1 (OFF_G + LAYERS*T)        // [f][t] float2 (c,s)*scale
#define OFF_TABT (OFF_TAB1 + F*T*2)        // [t][f] float2
#define OFF_ZRE  (OFF_TABT + F*T*2)
#define OFF_ZIM  (OFF_ZRE + B_ROWS*F)
#define OFF_RRE  (OFF_ZIM + B_ROWS*F)
#define OFF_RIM  (OFF_RRE + B_ROWS*T)

__global__ void kmax(const float* __restrict__ u, float* __restrict__ pmax, int n) {
    __shared__ float sm[256];
    float m = -1e30f;
    for (int i = blockIdx.x * blockDim.x + threadIdx.x; i < n; i += gridDim.x * blockDim.x)
        m = fmaxf(m, u[i]);
    sm[threadIdx.x] = m;
    __syncthreads();
    for (int s = 128; s > 0; s >>= 1) {
        if (threadIdx.x < s) sm[threadIdx.x] = fmaxf(sm[threadIdx.x], sm[threadIdx.x + s]);
        __syncthreads();
    }
    if (threadIdx.x == 0) pmax[blockIdx.x] = sm[0];
}

__global__ void kinit(float* __restrict__ ws) {
    __shared__ float sm[256];
    int t = threadIdx.x;
    sm[t] = ws[OFF_PMAX + t];
    __syncthreads();
    for (int s = 128; s > 0; s >>= 1) {
        if (t < s) sm[t] = fmaxf(sm[t], sm[t + s]);
        __syncthreads();
    }
    if (t == 0) {
        float m = fabsf(sm[0]);
        ws[OFF_SCALE]     = 5.0f / m;
        ws[OFF_SCALE + 1] = m / 5.0f;
    }
    for (int i = t; i < LAYERS * T; i += 256) ws[OFF_SUMS + i] = 0.0f;
}

// build twiddle tables: (cos, sin)(2*pi*f*t/T) / sqrt(T)
__global__ void ktab(float* __restrict__ ws) {
    int idx = blockIdx.x * 256 + threadIdx.x;      // 0 .. F*T-1
    if (idx >= F * T) return;
    int f = idx / T, t = idx % T;
    int ft = (f * t) & (T - 1);                    // periodic reduction, exact
    float ang = (float)ft * 0.012271846303085129f; // 2*pi/512
    float s, c;
    sincosf(ang, &s, &c);
    const float sc = 0.04419417382415922f;         // 1/sqrt(512)
    c *= sc; s *= sc;
    float2* tab1 = (float2*)(ws + OFF_TAB1);
    float2* tabT = (float2*)(ws + OFF_TABT);
    tab1[f * T + t] = make_float2(c, s);
    tabT[t * F + f] = make_float2(c, s);
}

// Phase A: Z = z @ idft ; R = H_prev + Z (H_prev = R_prev * g_prev) ; partial |R|^2 sums
// block = 256 threads = 4 waves; each wave owns one batch row, lanes span t.
__global__ __launch_bounds__(256) void kA(const float* __restrict__ u, float* __restrict__ ws, int layer) {
    __shared__ float zs_re[4][F], zs_im[4][F];
    __shared__ float red[T];
    __shared__ float gs[T];
    const int tid  = threadIdx.x;
    const int ty   = tid >> 6;
    const int lane = tid & 63;
    const int row  = blockIdx.x * 4 + ty;
    const float2* __restrict__ tab1 = (const float2*)(ws + OFF_TAB1);
    float* __restrict__ sums = ws + OFF_SUMS + layer * T;
    float* __restrict__ Rre = ws + OFF_RRE + (long)row * T;
    float* __restrict__ Rim = ws + OFF_RIM + (long)row * T;

    if (layer == 0) {
        float s = ws[OFF_SCALE];
        for (int f = lane; f < F; f += 64) {
            zs_re[ty][f] = s * u[row * 2 * F + 2 * f];
            zs_im[ty][f] = s * u[row * 2 * F + 2 * f + 1];
        }
    } else {
        const float* __restrict__ zre = ws + OFF_ZRE + (long)row * F;
        const float* __restrict__ zim = ws + OFF_ZIM + (long)row * F;
        for (int f = lane; f < F; f += 64) {
            zs_re[ty][f] = zre[f];
            zs_im[ty][f] = zim[f];
        }
        const float* __restrict__ gprev = ws + OFF_G + (layer - 1) * T;
        gs[tid] = gprev[tid];
        gs[tid + 256] = gprev[tid + 256];
    }
    red[tid] = 0.0f;
    red[tid + 256] = 0.0f;
    __syncthreads();

    float accR[8], accI[8];
#pragma unroll
    for (int k = 0; k < 8; k++) { accR[k] = 0.0f; accI[k] = 0.0f; }

    for (int f = 0; f < F; f++) {
        float zr = zs_re[ty][f], zi = zs_im[ty][f];
        const float2* __restrict__ trow = tab1 + f * T + lane;
#pragma unroll
        for (int k = 0; k < 8; k++) {
            float2 w = trow[64 * k];
            accR[k] += zr * w.x - zi * w.y;
            accI[k] += zr * w.y + zi * w.x;
        }
    }

#pragma unroll
    for (int k = 0; k < 8; k++) {
        int t = lane + 64 * k;
        float Rr, Ri;
        if (layer > 0) {
            float g = gs[t];
            Rr = Rre[t] * g + accR[k];
            Ri = Rim[t] * g + accI[k];
        } else {
            Rr = accR[k];
            Ri = accI[k];
        }
        Rre[t] = Rr;
        Rim[t] = Ri;
        atomicAdd(&red[t], Rr * Rr + Ri * Ri);
    }
    __syncthreads();
    atomicAdd(&sums[tid], red[tid]);
    atomicAdd(&sums[tid + 256], red[tid + 256]);
}

__global__ void kG(float* __restrict__ ws, const float* __restrict__ S1, const float* __restrict__ S2, int layer) {
    int t = threadIdx.x;
    float sum = ws[OFF_SUMS + layer * T + t];
    float rmean = sqrtf(sum * (1.0f / 16384.0f));
    float x = S1[0] * (rmean - S2[0]);
    ws[OFF_G + layer * T + t] = 1.0f / (1.0f + expf(-x));
}

// Phase B: h = (R*g) @ dft ; mode 0: z = u_s - h ; mode 1: out = h * (max/5)
// block = 256 threads = 16 rows x 16 f-groups; each thread owns 3 f values.
__global__ __launch_bounds__(256) void kB(const float* __restrict__ u, float* __restrict__ ws,
                                          float* __restrict__ out, int layer, int mode) {
    __shared__ float gs[T];
    const int tid  = threadIdx.x;
    const int rsub = tid >> 4;
    const int fg   = tid & 15;
    const int row  = blockIdx.x * 16 + rsub;
    const float2* __restrict__ tabT = (const float2*)(ws + OFF_TABT);
    const float* __restrict__ g = ws + OFF_G + layer * T;
    const float* __restrict__ Rre = ws + OFF_RRE + (long)row * T;
    const float* __restrict__ Rim = ws + OFF_RIM + (long)row * T;
    gs[tid] = g[tid];
    gs[tid + 256] = g[tid + 256];
    __syncthreads();

    float hr0 = 0, hr1 = 0, hr2 = 0, hi0 = 0, hi1 = 0, hi2 = 0;
#pragma unroll 4
    for (int t = 0; t < T; t++) {
        float gt = gs[t];
        float HR = Rre[t] * gt;
        float HI = Rim[t] * gt;
        float2 w0 = tabT[t * F + fg];
        float2 w1 = tabT[t * F + fg + 16];
        float2 w2 = tabT[t * F + fg + 32];
        // dft = (c, -s): h_re += HR*c + HI*s ; h_im += HI*c - HR*s
        hr0 += HR * w0.x + HI * w0.y;  hi0 += HI * w0.x - HR * w0.y;
        hr1 += HR * w1.x + HI * w1.y;  hi1 += HI * w1.x - HR * w1.y;
        hr2 += HR * w2.x + HI * w2.y;  hi2 += HI * w2.x - HR * w2.y;
    }

    if (mode == 0) {
        float s = ws[OFF_SCALE];
        float* __restrict__ zre = ws + OFF_ZRE + (long)row * F;
        float* __restrict__ zim = ws + OFF_ZIM + (long)row * F;
        zre[fg]      = s * u[row * 2 * F + 2 * fg]            - hr0;
        zim[fg]      = s * u[row * 2 * F + 2 * fg + 1]        - hi0;
        zre[fg + 16] = s * u[row * 2 * F + 2 * (fg + 16)]     - hr1;
        zim[fg + 16] = s * u[row * 2 * F + 2 * (fg + 16) + 1] - hi1;
        zre[fg + 32] = s * u[row * 2 * F + 2 * (fg + 32)]     - hr2;
        zim[fg + 32] = s * u[row * 2 * F + 2 * (fg + 32) + 1] - hi2;
    } else {
        float is = ws[OFF_SCALE + 1];
        out[(row * F + fg) * 2]          = hr0 * is;
        out[(row * F + fg) * 2 + 1]      = hi0 * is;
        out[(row * F + fg + 16) * 2]     = hr1 * is;
        out[(row * F + fg + 16) * 2 + 1] = hi1 * is;
        out[(row * F + fg + 32) * 2]     = hr2 * is;
        out[(row * F + fg + 32) * 2 + 1] = hi2 * is;
    }
}

extern "C" void kernel_launch(void* const* d_in, const int* in_sizes, int n_in,
                              void* d_out, int out_size, void* d_ws, size_t ws_size,
                              hipStream_t stream) {
    const float* u  = (const float*)d_in[0];
    const float* S1 = (const float*)d_in[1];
    const float* S2 = (const float*)d_in[2];
    float* out = (float*)d_out;
    float* ws  = (float*)d_ws;
    int n = in_sizes[0];

    kmax<<<256, 256, 0, stream>>>(u, ws + OFF_PMAX, n);
    kinit<<<1, 256, 0, stream>>>(ws);
    ktab<<<(F * T + 255) / 256, 256, 0, stream>>>(ws);

    for (int l = 0; l < LAYERS; l++) {
        kA<<<B_ROWS / 4, 256, 0, stream>>>(u, ws, l);
        kG<<<1, T, 0, stream>>>(ws, S1, S2, l);
        if (l < LAYERS - 1) kB<<<B_ROWS / 16, 256, 0, stream>>>(u, ws, out, l, 0);
    }
    kB<<<B_ROWS / 16, 256, 0, stream>>>(u, ws, out, LAYERS - 1, 1);
}

// Round 2
// 5361.855 us; speedup vs baseline: 1.2111x; 1.2111x over previous
//
#include <hip/hip_runtime.h>
#include <math.h>

#define NROWS 16384
#define F 48
#define FC 96                      // f components (re/im interleaved count)
#define T 512
#define LAYERS 16

// workspace layout (float offsets)
#define OFF_PMAX 0                                  // 256
#define OFF_SCALE 256                               // [0]=5/max, [1]=max/5
#define OFF_SUMS 512                                // LAYERS*T
#define OFF_TAB  (OFF_SUMS + LAYERS*T)              // [t][f] float2 (c,s)*sc
#define OFF_UT   (OFF_TAB + T*F*2)                  // [fc][row], scaled by 5/max
#define OFF_Z    (OFF_UT + FC*NROWS)                // [fc][row]
#define OFF_R    (OFF_Z + FC*NROWS)                 // [t][row] float2

__global__ void kmax(const float* __restrict__ u, float* __restrict__ pmax, int n) {
    __shared__ float sm[256];
    float m = -1e30f;
    for (int i = blockIdx.x * blockDim.x + threadIdx.x; i < n; i += gridDim.x * blockDim.x)
        m = fmaxf(m, u[i]);
    sm[threadIdx.x] = m;
    __syncthreads();
    for (int s = 128; s > 0; s >>= 1) {
        if (threadIdx.x < s) sm[threadIdx.x] = fmaxf(sm[threadIdx.x], sm[threadIdx.x + s]);
        __syncthreads();
    }
    if (threadIdx.x == 0) pmax[blockIdx.x] = sm[0];
}

__global__ void kinit(float* __restrict__ ws) {
    __shared__ float sm[256];
    int t = threadIdx.x;
    sm[t] = ws[OFF_PMAX + t];
    __syncthreads();
    for (int s = 128; s > 0; s >>= 1) {
        if (t < s) sm[t] = fmaxf(sm[t], sm[t + s]);
        __syncthreads();
    }
    if (t == 0) {
        float m = fabsf(sm[0]);
        ws[OFF_SCALE]     = 5.0f / m;
        ws[OFF_SCALE + 1] = m / 5.0f;
    }
    for (int i = t; i < LAYERS * T; i += 256) ws[OFF_SUMS + i] = 0.0f;
}

// twiddle table: tab[t][f] = (cos, sin)(2*pi*f*t/T) / sqrt(T)
__global__ void ktab(float* __restrict__ ws) {
    int idx = blockIdx.x * 256 + threadIdx.x;      // 0 .. T*F-1
    if (idx >= T * F) return;
    int t = idx / F, f = idx - t * F;
    int ft = (f * t) & (T - 1);                    // exact periodic reduction
    float ang = (float)ft * 0.012271846303085129f; // 2*pi/512
    float s, c;
    sincosf(ang, &s, &c);
    const float sc = 0.04419417382415922f;         // 1/sqrt(512)
    float2* tab = (float2*)(ws + OFF_TAB);
    tab[t * F + f] = make_float2(c * sc, s * sc);
}

// transpose u [row][fc] -> u_t [fc][row], scaled by 5/max
__global__ void ktr(const float* __restrict__ u, float* __restrict__ ws) {
    int i = blockIdx.x * 256 + threadIdx.x;        // 0 .. FC*NROWS-1
    int fc = i >> 14;                              // NROWS = 2^14
    int row = i & (NROWS - 1);
    float s = ws[OFF_SCALE];
    ws[OFF_UT + i] = s * u[row * FC + fc];
}

// Phase A: R[t][row] = g_{l-1}[t]*R_old + sum_f z[f]*w[f][t] ; accumulate |R|^2 sums
// block = 512 threads = 8 waves; lane = row (64 rows/block); wave = 64-t chunk.
__global__ __launch_bounds__(512) void kA(float* __restrict__ ws,
                                          const float* __restrict__ S1,
                                          const float* __restrict__ S2, int layer) {
    __shared__ float gs[T];
    const int tid  = threadIdx.x;
    const int wv   = __builtin_amdgcn_readfirstlane(threadIdx.x >> 6); // wave-uniform
    const int lane = tid & 63;
    const int row  = blockIdx.x * 64 + lane;

    if (layer > 0) {
        float sum = ws[OFF_SUMS + (layer - 1) * T + tid];
        float rm = sqrtf(sum * (1.0f / 16384.0f));
        gs[tid] = 1.0f / (1.0f + expf(-S1[0] * (rm - S2[0])));
    }
    __syncthreads();

    const float2* __restrict__ tab = (const float2*)(ws + OFF_TAB);
    const float* __restrict__ zsrc = ws + (layer == 0 ? OFF_UT : OFF_Z);
    float2* __restrict__ R = (float2*)(ws + OFF_R);
    float* __restrict__ sums = ws + OFF_SUMS + layer * T;

    // z for this lane's row: 96 values in registers
    float zr[F], zi[F];
#pragma unroll
    for (int f = 0; f < F; f++) {
        zr[f] = zsrc[(2 * f) * NROWS + row];
        zi[f] = zsrc[(2 * f + 1) * NROWS + row];
    }

    const int t0 = wv * 64;
    for (int tt = 0; tt < 64; tt++) {
        int t = t0 + tt;
        float2* Rp = R + (long)t * NROWS + row;
        float2 ro = make_float2(0.0f, 0.0f);
        if (layer > 0) ro = *Rp;                   // independent of f-loop: issues early
        const float2* __restrict__ w = tab + t * F; // wave-uniform -> scalar path
        float ar0 = 0.f, ar1 = 0.f, ai0 = 0.f, ai1 = 0.f;  // 4 indep chains
#pragma unroll
        for (int f = 0; f < F; f++) {
            float2 wf = w[f];
            ar0 = fmaf(zr[f], wf.x, ar0);
            ar1 = fmaf(zi[f], wf.y, ar1);
            ai0 = fmaf(zr[f], wf.y, ai0);
            ai1 = fmaf(zi[f], wf.x, ai1);
        }
        float Rr = ar0 - ar1;
        float Ri = ai0 + ai1;
        if (layer > 0) {
            float g = gs[t];
            Rr = fmaf(g, ro.x, Rr);
            Ri = fmaf(g, ro.y, Ri);
        }
        *Rp = make_float2(Rr, Ri);
        float p = Rr * Rr + Ri * Ri;
#pragma unroll
        for (int s = 32; s > 0; s >>= 1) p += __shfl_xor(p, s, 64);
        if (lane == 0) atomicAdd(&sums[t], p);
    }
}

// Phase B: h[f] = sum_t g[t]*R[t] * conj(w[f][t]) ; z_next = u_s - h  (or out = h*max/5)
// block = 512 threads = 8 waves; lane = row; wave = 64-t chunk; LDS reduce over waves.
__global__ __launch_bounds__(512) void kB(float* __restrict__ ws,
                                          const float* __restrict__ S1,
                                          const float* __restrict__ S2,
                                          float* __restrict__ out, int layer) {
    __shared__ float gs[T];
    __shared__ float zred[FC][64];                 // 24 KB
    const int tid  = threadIdx.x;
    const int wv   = __builtin_amdgcn_readfirstlane(threadIdx.x >> 6);
    const int lane = tid & 63;
    const int rowbase = blockIdx.x * 64;
    const int row  = rowbase + lane;

    {
        float sum = ws[OFF_SUMS + layer * T + tid];
        float rm = sqrtf(sum * (1.0f / 16384.0f));
        gs[tid] = 1.0f / (1.0f + expf(-S1[0] * (rm - S2[0])));
    }
    for (int i = tid; i < FC * 64; i += 512) ((float*)zred)[i] = 0.0f;
    __syncthreads();

    const float2* __restrict__ tab = (const float2*)(ws + OFF_TAB);
    const float2* __restrict__ R = (const float2*)(ws + OFF_R);

    float hr[F], hi[F];
#pragma unroll
    for (int f = 0; f < F; f++) { hr[f] = 0.0f; hi[f] = 0.0f; }

    const int t0 = wv * 64;
    float2 rv = R[(long)t0 * NROWS + row];
    for (int tt = 0; tt < 64; tt++) {
        int t = t0 + tt;
        int tn = (tt == 63) ? t : (t + 1);
        float2 rvn = R[(long)tn * NROWS + row];    // prefetch next iter
        float g = gs[t];
        float HR = g * rv.x;
        float HI = g * rv.y;
        const float2* __restrict__ w = tab + t * F; // wave-uniform -> scalar path
#pragma unroll
        for (int f = 0; f < F; f++) {
            float2 wf = w[f];
            hr[f] = fmaf(HR, wf.x, hr[f]);
            hr[f] = fmaf(HI, wf.y, hr[f]);
            hi[f] = fmaf(HI, wf.x, hi[f]);
            hi[f] = fmaf(-HR, wf.y, hi[f]);
        }
        rv = rvn;
    }

    // reduce the 8 waves' partials
#pragma unroll
    for (int f = 0; f < F; f++) {
        atomicAdd(&zred[2 * f][lane], hr[f]);
        atomicAdd(&zred[2 * f + 1][lane], hi[f]);
    }
    __syncthreads();

    if (layer < LAYERS - 1) {
        const float* __restrict__ ut = ws + OFF_UT;
        float* __restrict__ z = ws + OFF_Z;
        for (int i = tid; i < FC * 64; i += 512) {
            int fc = i >> 6; int r = i & 63;
            z[fc * NROWS + rowbase + r] = ut[fc * NROWS + rowbase + r] - zred[fc][r];
        }
    } else {
        float is = ws[OFF_SCALE + 1];
        for (int i = tid; i < FC * 64; i += 512) {
            int fc = i >> 6; int r = i & 63;
            out[(rowbase + r) * FC + fc] = zred[fc][r] * is;
        }
    }
}

extern "C" void kernel_launch(void* const* d_in, const int* in_sizes, int n_in,
                              void* d_out, int out_size, void* d_ws, size_t ws_size,
                              hipStream_t stream) {
    const float* u  = (const float*)d_in[0];
    const float* S1 = (const float*)d_in[1];
    const float* S2 = (const float*)d_in[2];
    float* out = (float*)d_out;
    float* ws  = (float*)d_ws;
    int n = in_sizes[0];

    kmax<<<256, 256, 0, stream>>>(u, ws + OFF_PMAX, n);
    kinit<<<1, 256, 0, stream>>>(ws);
    ktab<<<(T * F + 255) / 256, 256, 0, stream>>>(ws);
    ktr<<<(FC * NROWS) / 256, 256, 0, stream>>>(u, ws);

    for (int l = 0; l < LAYERS; l++) {
        kA<<<NROWS / 64, 512, 0, stream>>>(ws, S1, S2, l);
        kB<<<NROWS / 64, 512, 0, stream>>>(ws, S1, S2, out, l);
    }
}

// Round 3
// 1545.006 us; speedup vs baseline: 4.2030x; 3.4704x over previous
//
#include <hip/hip_runtime.h>
#include <math.h>

#define NROWS 16384
#define FC 96
#define T 512
#define NRI 1024
#define LAYERS 16

typedef _Float16 f16;
typedef _Float16 half8 __attribute__((ext_vector_type(8)));
typedef float floatx4 __attribute__((ext_vector_type(4)));

// ws float offsets
#define OFF_PMAX 0                               // 256
#define OFF_SCALE 256                            // [0]=5/max, [1]=max/5
#define OFF_SUMS 512                             // LAYERS*NRI  (per-n |C|^2 sums)
#define OFF_W1  (OFF_SUMS + LAYERS*NRI)          // 98304 f16 = 49152 floats (frag-linear hi)
#define OFF_W1L (OFF_W1 + 49152)
#define OFF_W2  (OFF_W1L + 49152)
#define OFF_W2L (OFF_W2 + 49152)
#define OFF_ZH  (OFF_W2L + 49152)                // 16384*96 f16 = 786432 floats
#define OFF_ZL  (OFF_ZH + 786432)
#define OFF_R   (OFF_ZL + 786432)                // 16384*1024 fp32 [b][n]

__global__ void kmax(const float* __restrict__ u, float* __restrict__ pmax, int n) {
    __shared__ float sm[256];
    float m = -1e30f;
    for (int i = blockIdx.x * blockDim.x + threadIdx.x; i < n; i += gridDim.x * blockDim.x)
        m = fmaxf(m, u[i]);
    sm[threadIdx.x] = m;
    __syncthreads();
    for (int s = 128; s > 0; s >>= 1) {
        if (threadIdx.x < s) sm[threadIdx.x] = fmaxf(sm[threadIdx.x], sm[threadIdx.x + s]);
        __syncthreads();
    }
    if (threadIdx.x == 0) pmax[blockIdx.x] = sm[0];
}

__global__ void kinit(float* __restrict__ ws) {
    __shared__ float sm[256];
    int t = threadIdx.x;
    sm[t] = ws[OFF_PMAX + t];
    __syncthreads();
    for (int s = 128; s > 0; s >>= 1) {
        if (t < s) sm[t] = fmaxf(sm[t], sm[t + s]);
        __syncthreads();
    }
    if (t == 0) {
        float m = fabsf(sm[0]);
        ws[OFF_SCALE]     = 5.0f / m;
        ws[OFF_SCALE + 1] = m / 5.0f;
    }
    for (int i = t; i < LAYERS * NRI; i += 256) ws[OFF_SUMS + i] = 0.0f;
}

// Build W1 (idft) and W2 (dft) in MFMA B-fragment-linear order, split f16 hi/lo.
// Frag element: value = B[k][n] with k = kc*32 + (lane>>4)*8 + j, n = nt*16 + (lane&15).
// W1 [96 x 1024]: col n: t=n>>1, e=n&1; row k: f=k>>1, q=k&1.
//   e=0 (Z_re): q0 -> c, q1 -> -s ; e=1 (Z_im): q0 -> s, q1 -> c.
// W2 [1024 x 96]: row k: t=k>>1, q=k&1 (0=HR,1=HI); col n: f=n>>1, e=n&1.
//   e=0 (h_re): q0 -> c, q1 -> s ; e=1 (h_im): q0 -> -s, q1 -> c.
__global__ void kwf(float* __restrict__ ws) {
    int idx = blockIdx.x * 256 + threadIdx.x;
    if (idx >= 2 * 98304) return;
    int which = idx >= 98304;
    int id = which ? idx - 98304 : idx;
    int j = id & 7, lane = (id >> 3) & 63, rem = id >> 9;
    int k, n;
    if (!which) { int kc = rem % 3,  nt = rem / 3;  k = kc*32 + (lane>>4)*8 + j; n = nt*16 + (lane&15); }
    else        { int kc = rem & 31, nt = rem >> 5; k = kc*32 + (lane>>4)*8 + j; n = nt*16 + (lane&15); }
    int t, f, q, e;
    if (!which) { t = n >> 1; e = n & 1; f = k >> 1; q = k & 1; }
    else        { t = k >> 1; q = k & 1; f = n >> 1; e = n & 1; }
    int ft = (f * t) & (T - 1);
    float sv, cv;
    sincosf((float)ft * 0.012271846303085129f, &sv, &cv);   // 2*pi/512
    const float sc = 0.04419417382415922f;                  // 1/sqrt(512)
    cv *= sc; sv *= sc;
    float val;
    if (!which) val = (e == 0) ? (q == 0 ? cv : -sv) : (q == 0 ?  sv : cv);
    else        val = (e == 0) ? (q == 0 ? cv :  sv) : (q == 0 ? -sv : cv);
    f16 hi = (f16)val;
    f16 lo = (f16)(val - (float)hi);
    f16* H = (f16*)(ws + (which ? OFF_W2 : OFF_W1));
    f16* L = (f16*)(ws + (which ? OFF_W2L : OFF_W1L));
    H[id] = hi;
    L[id] = lo;
}

// z0 = (5/max)*u, split f16 hi/lo, [b][fc] row-major
__global__ void kz0(const float* __restrict__ u, float* __restrict__ ws) {
    int i = blockIdx.x * 256 + threadIdx.x;
    float s = ws[OFF_SCALE];
    float z = s * u[i];
    f16 h = (f16)z;
    ((f16*)(ws + OFF_ZH))[i] = h;
    ((f16*)(ws + OFF_ZL))[i] = (f16)(z - (float)h);
}

// Phase A: C = zri x W1 (M=16384,N=1024,K=96); R = g_{l-1}*R_old + C; sums2[n] += sum_b C^2
// 256 thr = 4 waves; wave = 16 rows; block = 64 rows x 256 cols; grid = 256 m x 4 n.
__global__ __launch_bounds__(256, 4) void kA(float* __restrict__ ws,
                                             const float* __restrict__ S1,
                                             const float* __restrict__ S2, int layer) {
    __shared__ float garr[256];
    __shared__ float lsum[256];
    const int tid = threadIdx.x;
    const int bm = blockIdx.x >> 2;
    const int bn = blockIdx.x & 3;
    const int wv = tid >> 6;
    const int lane = tid & 63;
    const int quad = lane >> 4;
    const int l15 = lane & 15;

    if (layer > 0) {
        int n = bn * 256 + tid;
        int t = n >> 1;
        const float* sp = ws + OFF_SUMS + (layer - 1) * NRI;
        float sum = sp[2 * t] + sp[2 * t + 1];
        float rm = sqrtf(sum * (1.0f / 16384.0f));
        garr[tid] = 1.0f / (1.0f + expf(-S1[0] * (rm - S2[0])));
    }
    lsum[tid] = 0.0f;
    __syncthreads();

    const int m0 = bm * 64 + wv * 16;
    const int arow = m0 + l15;
    const f16* __restrict__ zh = (const f16*)(ws + OFF_ZH);
    const f16* __restrict__ zl = (const f16*)(ws + OFF_ZL);
    half8 Ah[3], Al[3];
#pragma unroll
    for (int kc = 0; kc < 3; kc++) {
        Ah[kc] = *(const half8*)(zh + arow * FC + kc * 32 + quad * 8);
        Al[kc] = *(const half8*)(zl + arow * FC + kc * 32 + quad * 8);
    }
    const f16* __restrict__ w1h = (const f16*)(ws + OFF_W1);
    const f16* __restrict__ w1l = (const f16*)(ws + OFF_W1L);
    float* __restrict__ R = ws + OFF_R;
    float* __restrict__ gsum = ws + OFF_SUMS + layer * NRI;

    for (int nt = 0; nt < 16; nt++) {
        const int ntg = bn * 16 + nt;                      // global 16-col tile
        const f16* bh = w1h + ((long)(ntg * 3) * 64 + lane) * 8;
        const f16* bl = w1l + ((long)(ntg * 3) * 64 + lane) * 8;
        floatx4 acc = {0.0f, 0.0f, 0.0f, 0.0f};
#pragma unroll
        for (int kc = 0; kc < 3; kc++) {
            half8 Bh = *(const half8*)(bh + kc * 512);
            half8 Bl = *(const half8*)(bl + kc * 512);
            acc = __builtin_amdgcn_mfma_f32_16x16x32_f16(Ah[kc], Bh, acc, 0, 0, 0);
            acc = __builtin_amdgcn_mfma_f32_16x16x32_f16(Ah[kc], Bl, acc, 0, 0, 0);
            acc = __builtin_amdgcn_mfma_f32_16x16x32_f16(Al[kc], Bh, acc, 0, 0, 0);
        }
        const int ncol = bn * 256 + nt * 16 + l15;
        float* Rp = R + (long)(m0 + quad * 4) * NRI + ncol;
        float p = 0.0f;
        if (layer > 0) {
            float g = garr[nt * 16 + l15];
#pragma unroll
            for (int r = 0; r < 4; r++) {
                float Rr = fmaf(g, Rp[(long)r * NRI], acc[r]);
                Rp[(long)r * NRI] = Rr;
                p = fmaf(Rr, Rr, p);
            }
        } else {
#pragma unroll
            for (int r = 0; r < 4; r++) {
                float Rr = acc[r];
                Rp[(long)r * NRI] = Rr;
                p = fmaf(Rr, Rr, p);
            }
        }
        p += __shfl_xor(p, 16, 64);
        p += __shfl_xor(p, 32, 64);
        if (lane < 16) atomicAdd(&lsum[nt * 16 + lane], p);
    }
    __syncthreads();
    atomicAdd(&gsum[bn * 256 + tid], lsum[tid]);
}

// Phase B: h = (g*R)ri x W2 (M=16384,N=96,K=1024); z = u_s - h (or out = h*max/5)
// 256 thr = 4 waves; block = 16 rows; waves split K (256 each); LDS fp32 reduce.
__global__ __launch_bounds__(256, 4) void kB(const float* __restrict__ u, float* __restrict__ ws,
                                             const float* __restrict__ S1,
                                             const float* __restrict__ S2,
                                             float* __restrict__ out, int layer) {
    __shared__ float garr[NRI];
    __shared__ float hred[16 * FC];
    const int tid = threadIdx.x;
    const int wv = tid >> 6;
    const int lane = tid & 63;
    const int quad = lane >> 4;
    const int l15 = lane & 15;
    const int m0 = blockIdx.x * 16;

    for (int i = tid; i < NRI; i += 256) {
        int t = i >> 1;
        const float* sp = ws + OFF_SUMS + layer * NRI;
        float sum = sp[2 * t] + sp[2 * t + 1];
        float rm = sqrtf(sum * (1.0f / 16384.0f));
        garr[i] = 1.0f / (1.0f + expf(-S1[0] * (rm - S2[0])));
    }
    for (int i = tid; i < 16 * FC; i += 256) hred[i] = 0.0f;
    __syncthreads();

    const float* __restrict__ R = ws + OFF_R;
    const f16* __restrict__ w2h = (const f16*)(ws + OFF_W2);
    const f16* __restrict__ w2l = (const f16*)(ws + OFF_W2L);
    const int row = m0 + l15;

    floatx4 acc[6];
#pragma unroll
    for (int nt = 0; nt < 6; nt++) acc[nt] = (floatx4){0.0f, 0.0f, 0.0f, 0.0f};

    for (int kc8 = 0; kc8 < 8; kc8++) {
        const int koct = wv * 256 + kc8 * 32 + quad * 8;
        const float* rp = R + (long)row * NRI + koct;
        float Hf[8];
#pragma unroll
        for (int j = 0; j < 8; j++) Hf[j] = rp[j] * garr[koct + j];
        half8 Hh, Hl;
#pragma unroll
        for (int j = 0; j < 8; j++) {
            f16 h = (f16)Hf[j];
            Hh[j] = h;
            Hl[j] = (f16)(Hf[j] - (float)h);
        }
        const int kcg = wv * 8 + kc8;
#pragma unroll
        for (int nt = 0; nt < 6; nt++) {
            half8 Bh = *(const half8*)(w2h + ((long)(nt * 32 + kcg) * 64 + lane) * 8);
            half8 Bl = *(const half8*)(w2l + ((long)(nt * 32 + kcg) * 64 + lane) * 8);
            acc[nt] = __builtin_amdgcn_mfma_f32_16x16x32_f16(Hh, Bh, acc[nt], 0, 0, 0);
            acc[nt] = __builtin_amdgcn_mfma_f32_16x16x32_f16(Hh, Bl, acc[nt], 0, 0, 0);
            acc[nt] = __builtin_amdgcn_mfma_f32_16x16x32_f16(Hl, Bh, acc[nt], 0, 0, 0);
        }
    }
#pragma unroll
    for (int nt = 0; nt < 6; nt++) {
#pragma unroll
        for (int r = 0; r < 4; r++)
            atomicAdd(&hred[(quad * 4 + r) * FC + nt * 16 + l15], acc[nt][r]);
    }
    __syncthreads();

    if (layer < LAYERS - 1) {
        float s = ws[OFF_SCALE];
        f16* __restrict__ zh = (f16*)(ws + OFF_ZH);
        f16* __restrict__ zl = (f16*)(ws + OFF_ZL);
        for (int i = tid; i < 16 * FC; i += 256) {
            int lr = i / FC, fc = i - lr * FC;
            long gi = (long)(m0 + lr) * FC + fc;
            float z = fmaf(s, u[gi], -hred[i]);
            f16 h = (f16)z;
            zh[gi] = h;
            zl[gi] = (f16)(z - (float)h);
        }
    } else {
        float is = ws[OFF_SCALE + 1];
        for (int i = tid; i < 16 * FC; i += 256) {
            int lr = i / FC, fc = i - lr * FC;
            long gi = (long)(m0 + lr) * FC + fc;
            out[gi] = hred[i] * is;
        }
    }
}

extern "C" void kernel_launch(void* const* d_in, const int* in_sizes, int n_in,
                              void* d_out, int out_size, void* d_ws, size_t ws_size,
                              hipStream_t stream) {
    const float* u  = (const float*)d_in[0];
    const float* S1 = (const float*)d_in[1];
    const float* S2 = (const float*)d_in[2];
    float* out = (float*)d_out;
    float* ws  = (float*)d_ws;
    int n = in_sizes[0];

    kmax<<<256, 256, 0, stream>>>(u, ws + OFF_PMAX, n);
    kinit<<<1, 256, 0, stream>>>(ws);
    kwf<<<768, 256, 0, stream>>>(ws);
    kz0<<<(NROWS * FC) / 256, 256, 0, stream>>>(u, ws);

    for (int l = 0; l < LAYERS; l++) {
        kA<<<1024, 256, 0, stream>>>(ws, S1, S2, l);
        kB<<<1024, 256, 0, stream>>>(u, ws, S1, S2, out, l);
    }
}